// Round 7
// baseline (737.802 us; speedup 1.0000x reference)
//
#include <hip/hip_runtime.h>
#include <hip/hip_cooperative_groups.h>
#include <stdint.h>

namespace cg = cooperative_groups;

// Key space: ((b*512 + x)*512 + y)*512 + z, b in {0,1} -> 2^28 keys.
// bucket = key >> 17 (2048 buckets); per-bucket 2^17-key bitmap lives only in
// LDS (32 KB), 2 bits/key: bit0 = union membership, bit1 = m present & >0.5.
#define KEYSPACE     (1u << 28)
#define NBUCKET      2048u
#define BUCKET_KEYS  (KEYSPACE / NBUCKET)    // 131072 keys per bucket
#define BUCKET_WORDS (BUCKET_KEYS / 16u)     // 8192 words = 32 KB LDS bitmap
#define BUCKET_CAP   4096u                   // entries per bucket (avg ~1953, +6sigma ~2217)
#define UMASK        0x55555555u             // union bits (even positions)
#define RECS_CAP     1024u                   // survivor records per bucket (avg ~244)
#define NBLK         512                     // cooperative grid: 2 blocks/CU x 256 CUs
#define NTHR         256
#define BPB          ((int)NBUCKET / NBLK)   // 4 buckets per block in build phase

__device__ __forceinline__ uint32_t encode4(int4 c) {
    return ((((uint32_t)c.x * 512u + (uint32_t)c.y) * 512u + (uint32_t)c.z) * 512u) + (uint32_t)c.w;
}

__global__ __launch_bounds__(NTHR) void fused(const int* __restrict__ xC,
                                              const float* __restrict__ xF,
                                              const int* __restrict__ mC,
                                              const float* __restrict__ mF,
                                              float* __restrict__ out,
                                              uint2* __restrict__ barr,
                                              uint32_t* __restrict__ bcnt,
                                              uint32_t* __restrict__ rcount,
                                              uint32_t* __restrict__ Btot,
                                              uint32_t* __restrict__ Boff,
                                              uint2* __restrict__ records,
                                              int Nx, int Nm, uint32_t out4) {
    // 60.4 KB static LDS -> 2 blocks/CU (120.8 <= 160 KB), grid 512 co-resident.
    __shared__ uint32_t hist[NBUCKET];      // 8 KB (bin: histogram, then cursor)
    __shared__ uint32_t base_[NBUCKET];     // 8 KB (bin: reserved base)
    __shared__ uint32_t bmp[BUCKET_WORDS];  // 32 KB (build: bucket bitmap)
    __shared__ uint32_t gpre[512];          // 2 KB (build: per-group prefix)
    __shared__ uint32_t sdata[NTHR];        // 1 KB (scans)
    __shared__ uint2    recs[RECS_CAP];     // 8 KB (build: survivor staging)
    __shared__ uint32_t nrec, rbase;

    cg::grid_group grid = cg::this_grid();
    int t = threadIdx.x;
    int blk = blockIdx.x;
    int total = Nx + Nm;

    // ---------------- Phase A: bin entries into per-bucket arrays ----------------
    // Entry: .x = low17 key-offset | mgood<<17 | isx<<18 ; .y = x row index.
    int epb = (total + NBLK - 1) / NBLK;
    int start = blk * epb;
    int end = min(start + epb, total);

    for (int q = t; q < (int)NBUCKET; q += NTHR) hist[q] = 0u;
    __syncthreads();
    for (int e = start + t; e < end; e += NTHR) {
        uint32_t k = (e < Nx) ? encode4(reinterpret_cast<const int4*>(xC)[e])
                              : encode4(reinterpret_cast<const int4*>(mC)[e - Nx]);
        atomicAdd(&hist[k >> 17], 1u);
    }
    __syncthreads();
    for (int q = t; q < (int)NBUCKET; q += NTHR) {
        uint32_t h = hist[q];
        base_[q] = h ? atomicAdd(&bcnt[q], h) : 0u;
        hist[q] = 0u;  // becomes cursor
    }
    __syncthreads();
    for (int e = start + t; e < end; e += NTHR) {
        uint32_t k; uint2 pl;
        if (e < Nx) {
            k = encode4(reinterpret_cast<const int4*>(xC)[e]);
            pl.x = (k & (BUCKET_KEYS - 1u)) | (1u << 18);
            pl.y = (uint32_t)e;
        } else {
            int j = e - Nx;
            k = encode4(reinterpret_cast<const int4*>(mC)[j]);
            pl.x = (k & (BUCKET_KEYS - 1u)) | ((mF[j] > 0.5f) ? (1u << 17) : 0u);
            pl.y = 0u;
        }
        uint32_t b = k >> 17;
        uint32_t pos = base_[b] + atomicAdd(&hist[b], 1u);
        barr[(size_t)b * BUCKET_CAP + pos] = pl;
    }
    grid.sync();

    // ---------------- Phase B: build 4 buckets per block ----------------
    for (int bk = 0; bk < BPB; ++bk) {
        uint32_t b = (uint32_t)(blk * BPB + bk);
        {
            uint4 z = make_uint4(0u, 0u, 0u, 0u);
            uint4* bz = reinterpret_cast<uint4*>(bmp);
            for (int q = t; q < (int)(BUCKET_WORDS / 4u); q += NTHR) bz[q] = z;
        }
        __syncthreads();
        uint32_t n = bcnt[b];
        const uint2* ba = barr + (size_t)b * BUCKET_CAP;
        for (uint32_t e = t; e < n; e += NTHR) {
            uint32_t pl = ba[e].x;
            uint32_t off = pl & (BUCKET_KEYS - 1u);
            uint32_t bits = 1u | (((pl >> 17) & 1u) << 1);
            atomicOr(&bmp[off >> 4], bits << ((off & 15u) * 2u));
        }
        __syncthreads();

        // per-group popcount (512 groups of 256 keys) + block scan
        uint32_t c0 = 0u, c1 = 0u;
        {
            const uint32_t* w0 = bmp + (2 * t) * 16;
            const uint32_t* w1 = bmp + (2 * t + 1) * 16;
#pragma unroll
            for (int q = 0; q < 16; ++q) c0 += __popc(w0[q] & UMASK);
#pragma unroll
            for (int q = 0; q < 16; ++q) c1 += __popc(w1[q] & UMASK);
        }
        uint32_t s = c0 + c1;
        sdata[t] = s;
        __syncthreads();
        for (int off = 1; off < NTHR; off <<= 1) {
            uint32_t tmp = (t >= off) ? sdata[t - off] : 0u;
            __syncthreads();
            sdata[t] += tmp;
            __syncthreads();
        }
        uint32_t ex = sdata[t] - s;
        gpre[2 * t] = ex;
        gpre[2 * t + 1] = ex + c0;
        if (t == NTHR - 1) Btot[b] = sdata[NTHR - 1];
        if (t == 0) nrec = 0u;
        __syncthreads();

        // rank surviving x entries entirely in LDS, stage records
        for (uint32_t e = t; e < n; e += NTHR) {
            uint2 pe = ba[e];
            if (!(pe.x & (1u << 18))) continue;  // x entries only
            uint32_t off = pe.x & (BUCKET_KEYS - 1u);
            uint32_t w = off >> 4;
            uint32_t j2 = (off & 15u) * 2u;
            uint32_t word = bmp[w];
            if (!((word >> (j2 + 1u)) & 1u)) continue;  // mgood gate
            uint32_t g = off >> 8;
            uint32_t r = gpre[g];
            for (uint32_t q = g << 4; q < w; ++q) r += __popc(bmp[q] & UMASK);
            r += __popc(word & UMASK & ((1u << j2) - 1u));
            uint32_t pos = atomicAdd(&nrec, 1u);
            if (pos < RECS_CAP) recs[pos] = make_uint2(pe.y, (b << 17) | r);
        }
        __syncthreads();
        if (t == 0) rbase = atomicAdd(rcount, min(nrec, RECS_CAP));
        __syncthreads();
        uint32_t n2 = min(nrec, RECS_CAP);
        for (uint32_t q = t; q < n2; q += NTHR) records[rbase + q] = recs[q];
        __syncthreads();
    }
    grid.sync();

    // ---------------- Phase C: top scan (block 0) || zero output (all) ----------------
    if (blk == 0) {
        uint32_t v[8]; uint32_t s = 0u;
#pragma unroll
        for (int q = 0; q < 8; ++q) { v[q] = Btot[t * 8 + q]; s += v[q]; }
        sdata[t] = s;
        __syncthreads();
        for (int off = 1; off < NTHR; off <<= 1) {
            uint32_t tmp = (t >= off) ? sdata[t - off] : 0u;
            __syncthreads();
            sdata[t] += tmp;
            __syncthreads();
        }
        uint32_t ex = sdata[t] - s;
#pragma unroll
        for (int q = 0; q < 8; ++q) { Boff[t * 8 + q] = ex; ex += v[q]; }
    }
    {
        uint4 z = make_uint4(0u, 0u, 0u, 0u);
        uint4* o4 = reinterpret_cast<uint4*>(out);
        uint32_t gtid = (uint32_t)(blk * NTHR + t);
        for (uint32_t q = gtid; q < out4; q += (uint32_t)(NBLK * NTHR)) o4[q] = z;
    }
    grid.sync();

    // ---------------- Phase D: gather surviving rows ----------------
    uint32_t nr = *rcount;
    uint32_t gtid = (uint32_t)(blk * NTHR + t);
    for (uint32_t i = gtid; i < nr; i += (uint32_t)(NBLK * NTHR)) {
        uint2 rec = records[i];
        uint32_t r = Boff[rec.y >> 17] + (rec.y & (BUCKET_KEYS - 1u));
        const float4* f = reinterpret_cast<const float4*>(xF + (size_t)rec.x * 16u);
        float4 f0 = f[0], f1 = f[1], f2 = f[2], f3 = f[3];
        bool any =
            (f0.x > 0.f) | (f0.y > 0.f) | (f0.z > 0.f) | (f0.w > 0.f) |
            (f1.x > 0.f) | (f1.y > 0.f) | (f1.z > 0.f) | (f1.w > 0.f) |
            (f2.x > 0.f) | (f2.y > 0.f) | (f2.z > 0.f) | (f2.w > 0.f) |
            (f3.x > 0.f) | (f3.y > 0.f) | (f3.z > 0.f) | (f3.w > 0.f);
        if (!any) continue;
        float4* o = reinterpret_cast<float4*>(out + (size_t)r * 16u);
        o[0] = f0; o[1] = f1; o[2] = f2; o[3] = f3;
    }
}

extern "C" void kernel_launch(void* const* d_in, const int* in_sizes, int n_in,
                              void* d_out, int out_size, void* d_ws, size_t ws_size,
                              hipStream_t stream) {
    const int* xC = (const int*)d_in[0];
    const float* xF = (const float*)d_in[1];
    const int* mC = (const int*)d_in[2];
    const float* mF = (const float*)d_in[3];
    float* out = (float*)d_out;

    int Nx = in_sizes[1] / 16;
    int Nm = in_sizes[3];
    uint32_t out4 = (uint32_t)(out_size / 4);  // #uint4 in output

    // Workspace layout (bytes):
    //   [0, 64M)        barr    (2048 buckets x 4096 x uint2)
    //   [64M, 80M)      records (up to 2M uint2)
    //   [80M, +8K)      bcnt  (2048 u32)  } zeroed together
    //   [80M+8K, +4)    rcount (1 u32)    }
    //   [80M+12K, +8K)  Btot
    //   [80M+20K, +8K)  Boff
    uint8_t* ws = (uint8_t*)d_ws;
    uint2*    barr    = (uint2*)(ws);
    uint2*    records = (uint2*)(ws + (size_t)64 * 1024 * 1024);
    uint32_t* bcnt    = (uint32_t*)(ws + (size_t)80 * 1024 * 1024);
    uint32_t* rcount  = (uint32_t*)(ws + (size_t)80 * 1024 * 1024 + 8192);
    uint32_t* Btot    = (uint32_t*)(ws + (size_t)80 * 1024 * 1024 + 12288);
    uint32_t* Boff    = (uint32_t*)(ws + (size_t)80 * 1024 * 1024 + 20480);

    hipMemsetAsync(bcnt, 0, 8192 + 4, stream);  // bcnt + rcount

    void* args[] = {(void*)&xC, (void*)&xF, (void*)&mC, (void*)&mF, (void*)&out,
                    (void*)&barr, (void*)&bcnt, (void*)&rcount, (void*)&Btot,
                    (void*)&Boff, (void*)&records, (void*)&Nx, (void*)&Nm,
                    (void*)&out4};
    hipLaunchCooperativeKernel((const void*)fused, dim3(NBLK), dim3(NTHR),
                               args, 0, stream);
}

// Round 8
// 522.772 us; speedup vs baseline: 1.4113x; 1.4113x over previous
//
#include <hip/hip_runtime.h>
#include <stdint.h>

// Key space: ((b*512 + x)*512 + y)*512 + z, b in {0,1} -> 2^28 keys.
// bucket = key >> 17 (2048 buckets); per-bucket 2^17-key bitmap lives only in
// LDS (32 KB), 2 bits/key: bit0 = union membership, bit1 = m present & >0.5.
// LDS word index is XOR-swizzled (w ^ ((w>>5)&31)) so the popcount/scan's
// stride-32 read pattern spreads across banks (was: all lanes on one bank).
#define KEYSPACE     (1u << 28)
#define NBUCKET      2048u
#define BUCKET_KEYS  (KEYSPACE / NBUCKET)    // 131072 keys per bucket
#define BUCKET_WORDS (BUCKET_KEYS / 16u)     // 8192 words = 32 KB LDS bitmap
#define BUCKET_CAP   4096u                   // entries per bucket (avg ~1953)
#define EPB          8192                    // entries per bin block (489 blocks)
#define UMASK        0x55555555u             // union bits (even positions)
#define RECS_CAP     1024u                   // survivor records per bucket (avg ~244)

__device__ __forceinline__ uint32_t encode4(int4 c) {
    return ((((uint32_t)c.x * 512u + (uint32_t)c.y) * 512u + (uint32_t)c.z) * 512u) + (uint32_t)c.w;
}
__device__ __forceinline__ uint32_t swz(uint32_t w) { return w ^ ((w >> 5) & 31u); }

// Phase 1: zero the output (grid-stride streaming, overlaps with binning) and
// bin entries into per-bucket arrays via LDS histogram + block reserve.
// Entry: .x = low17 key-offset | mgood<<17 | isx<<18 ; .y = x row index.
__global__ __launch_bounds__(256) void bin_zero(const int* __restrict__ xC,
                                                const int* __restrict__ mC,
                                                const float* __restrict__ mF,
                                                uint2* __restrict__ barr,
                                                uint32_t* __restrict__ bcnt,
                                                float* __restrict__ out,
                                                uint32_t out4, int Nx, int Nm) {
    __shared__ uint32_t hist[NBUCKET];  // 8 KB (histogram, then cursor)
    __shared__ uint32_t base_[NBUCKET]; // 8 KB
    int t = threadIdx.x;
    int blk = blockIdx.x;
    uint32_t nthr = gridDim.x * 256u;

    // out-zero: pure streaming stores, mixes with the latency-bound bin work
    {
        uint4 z = make_uint4(0u, 0u, 0u, 0u);
        uint4* o4 = reinterpret_cast<uint4*>(out);
        for (uint32_t q = (uint32_t)blk * 256u + t; q < out4; q += nthr) o4[q] = z;
    }

    int total = Nx + Nm;
    int start = blk * EPB;
    int end = min(start + EPB, total);

    for (int q = t; q < (int)NBUCKET; q += 256) hist[q] = 0u;
    __syncthreads();

    // pass A: histogram
    for (int e = start + t; e < end; e += 256) {
        uint32_t k = (e < Nx) ? encode4(reinterpret_cast<const int4*>(xC)[e])
                              : encode4(reinterpret_cast<const int4*>(mC)[e - Nx]);
        atomicAdd(&hist[k >> 17], 1u);
    }
    __syncthreads();

    // block-level reserve
    for (int q = t; q < (int)NBUCKET; q += 256) {
        uint32_t h = hist[q];
        base_[q] = h ? atomicAdd(&bcnt[q], h) : 0u;
        hist[q] = 0u;  // becomes cursor
    }
    __syncthreads();

    // pass B: scatter payloads (chunk is L2-hot from pass A)
    for (int e = start + t; e < end; e += 256) {
        uint32_t k; uint2 pl;
        if (e < Nx) {
            k = encode4(reinterpret_cast<const int4*>(xC)[e]);
            pl.x = (k & (BUCKET_KEYS - 1u)) | (1u << 18);
            pl.y = (uint32_t)e;
        } else {
            int j = e - Nx;
            k = encode4(reinterpret_cast<const int4*>(mC)[j]);
            pl.x = (k & (BUCKET_KEYS - 1u)) | ((mF[j] > 0.5f) ? (1u << 17) : 0u);
            pl.y = 0u;
        }
        uint32_t b = k >> 17;
        uint32_t pos = base_[b] + atomicAdd(&hist[b], 1u);
        barr[(size_t)b * BUCKET_CAP + pos] = pl;
    }
}

// Phase 2: one block per bucket. Build the 32 KB bitmap in LDS (swizzled),
// popcount+scan group prefixes (group = 256 keys), rank surviving x entries
// entirely in LDS, emit compact records (.x = x row, .y = bucket<<17 | rank).
__global__ __launch_bounds__(256) void build_bucket(const uint2* __restrict__ barr,
                                                    const uint32_t* __restrict__ bcnt,
                                                    uint2* __restrict__ records,
                                                    uint32_t* __restrict__ rcount,
                                                    uint32_t* __restrict__ Btot) {
    __shared__ uint32_t bmp[BUCKET_WORDS];  // 32 KB (swizzled word index)
    __shared__ uint32_t gpre[512];          // per-group exclusive prefix
    __shared__ uint32_t sdata[256];
    __shared__ uint2 recs[RECS_CAP];        // 8 KB
    __shared__ uint32_t nrec, rbase;
    int t = threadIdx.x;
    uint32_t b = blockIdx.x;

    {
        uint4 z = make_uint4(0u, 0u, 0u, 0u);
        uint4* bz = reinterpret_cast<uint4*>(bmp);
        for (int q = t; q < (int)(BUCKET_WORDS / 4u); q += 256) bz[q] = z;
    }
    __syncthreads();

    uint32_t n = bcnt[b];
    const uint2* ba = barr + (size_t)b * BUCKET_CAP;

    // pass 1: build bitmap with LDS atomics (random banks)
    for (uint32_t e = t; e < n; e += 256u) {
        uint32_t pl = ba[e].x;
        uint32_t off = pl & (BUCKET_KEYS - 1u);
        uint32_t bits = 1u | (((pl >> 17) & 1u) << 1);
        atomicOr(&bmp[swz(off >> 4)], bits << ((off & 15u) * 2u));
    }
    __syncthreads();

    // per-group popcount (512 groups, 2 per thread) + block scan.
    // swz makes lane-bank = q ^ (t&31): conflict-free (2 lanes/bank).
    uint32_t c0 = 0u, c1 = 0u;
    {
        uint32_t b0 = 32u * (uint32_t)t, b1 = b0 + 16u;
#pragma unroll
        for (uint32_t q = 0; q < 16u; ++q) c0 += __popc(bmp[swz(b0 + q)] & UMASK);
#pragma unroll
        for (uint32_t q = 0; q < 16u; ++q) c1 += __popc(bmp[swz(b1 + q)] & UMASK);
    }
    uint32_t s = c0 + c1;
    sdata[t] = s;
    __syncthreads();
    for (int off = 1; off < 256; off <<= 1) {
        uint32_t tmp = (t >= off) ? sdata[t - off] : 0u;
        __syncthreads();
        sdata[t] += tmp;
        __syncthreads();
    }
    uint32_t ex = sdata[t] - s;
    gpre[2 * t] = ex;
    gpre[2 * t + 1] = ex + c0;
    if (t == 255) Btot[b] = sdata[255];
    if (t == 0) nrec = 0u;
    __syncthreads();

    // pass 2: rank surviving x entries in LDS, append records
    for (uint32_t e = t; e < n; e += 256u) {
        uint2 pe = ba[e];
        if (!(pe.x & (1u << 18))) continue;  // x entries only
        uint32_t off = pe.x & (BUCKET_KEYS - 1u);
        uint32_t w = off >> 4;
        uint32_t j2 = (off & 15u) * 2u;
        uint32_t word = bmp[swz(w)];
        if (!((word >> (j2 + 1u)) & 1u)) continue;  // mgood: m present & >0.5
        uint32_t g = off >> 8;
        uint32_t r = gpre[g];
        for (uint32_t q = g << 4; q < w; ++q) r += __popc(bmp[swz(q)] & UMASK);
        r += __popc(word & UMASK & ((1u << j2) - 1u));
        uint32_t pos = atomicAdd(&nrec, 1u);
        if (pos < RECS_CAP) recs[pos] = make_uint2(pe.y, (b << 17) | r);
    }
    __syncthreads();

    if (t == 0) rbase = atomicAdd(rcount, min(nrec, RECS_CAP));
    __syncthreads();
    uint32_t n2 = min(nrec, RECS_CAP);
    for (uint32_t q = t; q < n2; q += 256u) records[rbase + q] = recs[q];
}

// Exclusive scan of 2048 bucket totals (one block, 1024 threads x 2).
__global__ __launch_bounds__(1024) void scan_top(const uint32_t* __restrict__ Btot,
                                                 uint32_t* __restrict__ Boff) {
    __shared__ uint32_t sdata[1024];
    int t = threadIdx.x;
    uint32_t v0 = Btot[2 * t], v1 = Btot[2 * t + 1];
    uint32_t s = v0 + v1;
    sdata[t] = s;
    __syncthreads();
    for (int off = 1; off < 1024; off <<= 1) {
        uint32_t tmp = (t >= off) ? sdata[t - off] : 0u;
        __syncthreads();
        sdata[t] += tmp;
        __syncthreads();
    }
    uint32_t ex = sdata[t] - s;
    Boff[2 * t] = ex;
    Boff[2 * t + 1] = ex + v0;
}

// Final gather: record -> out[Boff[bucket] + local_rank] = xF[row] (if any>0).
__global__ __launch_bounds__(256) void gather_rows(const uint2* __restrict__ records,
                                                   const uint32_t* __restrict__ rcount,
                                                   const uint32_t* __restrict__ Boff,
                                                   const float* __restrict__ xF,
                                                   float* __restrict__ out) {
    uint32_t i = blockIdx.x * blockDim.x + threadIdx.x;
    if (i >= *rcount) return;
    uint2 rec = records[i];
    uint32_t r = Boff[rec.y >> 17] + (rec.y & (BUCKET_KEYS - 1u));

    const float4* f = reinterpret_cast<const float4*>(xF + (size_t)rec.x * 16u);
    float4 f0 = f[0], f1 = f[1], f2 = f[2], f3 = f[3];
    bool any =
        (f0.x > 0.f) | (f0.y > 0.f) | (f0.z > 0.f) | (f0.w > 0.f) |
        (f1.x > 0.f) | (f1.y > 0.f) | (f1.z > 0.f) | (f1.w > 0.f) |
        (f2.x > 0.f) | (f2.y > 0.f) | (f2.z > 0.f) | (f2.w > 0.f) |
        (f3.x > 0.f) | (f3.y > 0.f) | (f3.z > 0.f) | (f3.w > 0.f);
    if (!any) return;

    float4* o = reinterpret_cast<float4*>(out + (size_t)r * 16u);
    o[0] = f0; o[1] = f1; o[2] = f2; o[3] = f3;
}

extern "C" void kernel_launch(void* const* d_in, const int* in_sizes, int n_in,
                              void* d_out, int out_size, void* d_ws, size_t ws_size,
                              hipStream_t stream) {
    const int* xC = (const int*)d_in[0];
    const float* xF = (const float*)d_in[1];
    const int* mC = (const int*)d_in[2];
    const float* mF = (const float*)d_in[3];
    float* out = (float*)d_out;

    int Nx = in_sizes[1] / 16;
    int Nm = in_sizes[3];
    int total = Nx + Nm;
    uint32_t out4 = (uint32_t)(out_size / 4);  // #uint4 in output

    // Workspace layout (bytes):
    //   [0, 64M)        barr    (2048 buckets x 4096 x uint2)
    //   [64M, 80M)      records (up to 2M uint2)
    //   [80M, +8K)      bcnt  (2048 u32)  } zeroed together
    //   [80M+8K, +4)    rcount (1 u32)    }
    //   [80M+12K, +8K)  Btot
    //   [80M+20K, +8K)  Boff
    uint8_t* ws = (uint8_t*)d_ws;
    uint2*    barr    = (uint2*)(ws);
    uint2*    records = (uint2*)(ws + (size_t)64 * 1024 * 1024);
    uint32_t* bcnt    = (uint32_t*)(ws + (size_t)80 * 1024 * 1024);
    uint32_t* rcount  = (uint32_t*)(ws + (size_t)80 * 1024 * 1024 + 8192);
    uint32_t* Btot    = (uint32_t*)(ws + (size_t)80 * 1024 * 1024 + 12288);
    uint32_t* Boff    = (uint32_t*)(ws + (size_t)80 * 1024 * 1024 + 20480);

    hipMemsetAsync(bcnt, 0, 8192 + 4, stream);  // bcnt + rcount

    int nbin = (total + EPB - 1) / EPB;  // 489 blocks
    bin_zero<<<nbin, 256, 0, stream>>>(xC, mC, mF, barr, bcnt, out, out4, Nx, Nm);
    build_bucket<<<NBUCKET, 256, 0, stream>>>(barr, bcnt, records, rcount, Btot);
    scan_top<<<1, 1024, 0, stream>>>(Btot, Boff);
    gather_rows<<<(Nx + 255) / 256, 256, 0, stream>>>(records, rcount, Boff, xF, out);
}